// Round 11
// baseline (83.151 us; speedup 1.0000x reference)
//
#include <hip/hip_runtime.h>
#include <hip/hip_bf16.h>

#define Bn 64
#define Tn 512
#define Dn 512
#define Hn 128
#define BT (Bn*Tn)

typedef unsigned short u16;
typedef unsigned long long u64;
typedef __attribute__((ext_vector_type(8))) short bf16x8;
typedef __attribute__((ext_vector_type(4))) float f32x4;

__device__ __forceinline__ u16 f2bf(float f) {
  union { float f; unsigned u; } v; v.f = f;
  unsigned r = (v.u + 0x7FFFu + ((v.u >> 16) & 1u)) >> 16;
  return (u16)r;
}

__device__ __forceinline__ bf16x8 pack8(float4 a, float4 b) {
  bf16x8 o;
  o[0] = (short)f2bf(a.x); o[1] = (short)f2bf(a.y);
  o[2] = (short)f2bf(a.z); o[3] = (short)f2bf(a.w);
  o[4] = (short)f2bf(b.x); o[5] = (short)f2bf(b.y);
  o[6] = (short)f2bf(b.z); o[7] = (short)f2bf(b.w);
  return o;
}

// async global->LDS, 16B/lane; LDS dest = wave-uniform base (+lane*16 by HW)
__device__ __forceinline__ void gload16(const void* g, void* lds) {
  __builtin_amdgcn_global_load_lds(
      (const __attribute__((address_space(1))) unsigned int*)g,
      (__attribute__((address_space(3))) unsigned int*)lds, 16, 0, 0);
}

// ---------- prep: all three W -> bf16 (one launch) ----------
__global__ __launch_bounds__(256) void conv_w3(const float4* __restrict__ Wk,
                                               const float4* __restrict__ Wq,
                                               const float4* __restrict__ Wv,
                                               ushort4* __restrict__ out) {
  int idx = blockIdx.x * 256 + threadIdx.x;        // 3 * 16384
  int which = idx >> 14, j = idx & 16383;
  const float4* src = (which == 0) ? Wk : (which == 1) ? Wq : Wv;
  float4 v = src[j];
  ushort4 o; o.x = f2bf(v.x); o.y = f2bf(v.y); o.z = f2bf(v.z); o.w = f2bf(v.w);
  out[idx] = o;
}

// ---------- prep: dag transpose + bf16 + mask bits (fused) ----------
__global__ __launch_bounds__(256) void dag_tr(const float* __restrict__ dag,
                                              u16* __restrict__ dagT,
                                              u64* __restrict__ bits) {
  __shared__ float s[64][65];
  int bx = blockIdx.x & 7, by = blockIdx.x >> 3;
  int r0 = by * 64, c0 = bx * 64;
  int t = threadIdx.x;
  int c4 = t & 15, rr = t >> 4;
#pragma unroll
  for (int q = 0; q < 4; ++q) {
    int r = rr + q * 16;
    float4 v = *(const float4*)&dag[(size_t)(r0 + r) * Tn + c0 + c4 * 4];
    s[c4 * 4 + 0][r] = v.x; s[c4 * 4 + 1][r] = v.y;
    s[c4 * 4 + 2][r] = v.z; s[c4 * 4 + 3][r] = v.w;
  }
  __syncthreads();
#pragma unroll
  for (int q = 0; q < 4; ++q) {
    int il = rr + q * 16;
    ushort4 o;
    u64 b4 = 0;
#pragma unroll
    for (int r = 0; r < 4; ++r) {
      float v = s[il][c4 * 4 + r];
      ((u16*)&o)[r] = f2bf(v);
      b4 |= (u64)(v != 0.f) << (c4 * 4 + r);
    }
    *(ushort4*)&dagT[(size_t)(c0 + il) * Tn + r0 + c4 * 4] = o;
    b4 |= __shfl_xor(b4, 1, 64);
    b4 |= __shfl_xor(b4, 2, 64);
    b4 |= __shfl_xor(b4, 4, 64);
    b4 |= __shfl_xor(b4, 8, 64);
    if (c4 == 0) bits[(size_t)(c0 + il) * 8 + (r0 >> 6)] = b4;
  }
}

// ---------- stage 1: K,Q,V = swish(X W^T + b); LDS-bounced coalesced epilogue ----------
// grid BT/128, 512 threads (8 waves: wr in {0,1}, wc in {0..3}).
__global__ __launch_bounds__(512, 2) void qkv3(
    const float* __restrict__ X, const u16* __restrict__ Wcat,
    const float* __restrict__ bk, const float* __restrict__ bq,
    const float* __restrict__ bv,
    u16* __restrict__ Kb, u16* __restrict__ QT, u16* __restrict__ VT) {
  __shared__ u16 sm[32768];   // 64KB: A(16KB) | Bk | Bq | Bv; reused for epilogue bounce
  int m0 = blockIdx.x * 128;
  int tid = threadIdx.x, lane = tid & 63, wave = tid >> 6;
  int wr = wave >> 2, wc = wave & 3;
  int col0 = lane & 15, rg = lane >> 4, kcb = rg * 16;
  int swl = (col0 & 7) << 4;
  int xrow = tid >> 2, xcq = tid & 3;      // X staging: row, 16-elem quarter
  f32x4 acc[3][4][2] = {};
  const char* Wb = (const char*)Wcat;
  char* smb = (char*)sm;

  for (int kt = 0; kt < Dn; kt += 64) {
    // A: reg-stage X fp32 -> bf16, swizzled LDS write
    {
      const float4* src = (const float4*)(X + (size_t)(m0 + xrow) * Dn + kt + xcq * 16);
      float4 a0 = src[0], a1 = src[1], a2 = src[2], a3 = src[3];
      int sw = (xrow & 7) << 4;
      *(bf16x8*)(smb + xrow * 128 + ((xcq * 32) ^ sw)) = pack8(a0, a1);
      *(bf16x8*)(smb + xrow * 128 + ((xcq * 32 + 16) ^ sw)) = pack8(a2, a3);
    }
    // W: 48KB via gload16, pre-swizzled source
#pragma unroll
    for (int q = 0; q < 6; ++q) {
      int c2 = wave * 6 + q;
      int which = c2 >> 4, idx = c2 & 15;
      int flat = idx * 1024 + lane * 16;
      int row = flat >> 7, colb = flat & 127;
      int sw = (row & 7) << 4;
      gload16(Wb + (size_t)which * 131072 + (size_t)row * 1024 + (kt << 1) + (colb ^ sw),
              smb + 16384 + which * 16384 + idx * 1024);
    }
    __syncthreads();
    bf16x8 af[4][2];
#pragma unroll
    for (int m = 0; m < 4; ++m)
#pragma unroll
      for (int kk = 0; kk < 2; ++kk)
        af[m][kk] = *(const bf16x8*)(smb + (wr * 64 + m * 16 + col0) * 128 + ((kk * 64 + kcb) ^ swl));
#pragma unroll
    for (int which = 0; which < 3; ++which) {
      bf16x8 bfr[2][2];
#pragma unroll
      for (int n = 0; n < 2; ++n)
#pragma unroll
        for (int kk = 0; kk < 2; ++kk)
          bfr[n][kk] = *(const bf16x8*)(smb + 16384 + which * 16384 +
                                        (wc * 32 + n * 16 + col0) * 128 + ((kk * 64 + kcb) ^ swl));
#pragma unroll
      for (int kk = 0; kk < 2; ++kk)
#pragma unroll
        for (int m = 0; m < 4; ++m)
#pragma unroll
          for (int n = 0; n < 2; ++n)
            acc[which][m][n] = __builtin_amdgcn_mfma_f32_16x16x32_bf16(
                af[m][kk], bfr[n][kk], acc[which][m][n], 0, 0, 0);
    }
    __syncthreads();
  }

  // ---- epilogue: bounce each output through LDS -> full-line global stores ----
  // K (which=0): LDS layout [t][h], 32KB
  {
#pragma unroll
    for (int n = 0; n < 2; ++n) {
      int nl = wc * 32 + n * 16 + col0;
      float bs = bk[nl];
#pragma unroll
      for (int m = 0; m < 4; ++m)
#pragma unroll
        for (int r = 0; r < 4; ++r) {
          int tl = wr * 64 + m * 16 + rg * 4 + r;
          float x = acc[0][m][n][r] + bs;
          *(u16*)(smb + tl * 256 + ((nl * 2) ^ ((tl & 7) << 4))) = f2bf(x / (1.f + __expf(-x)));
        }
    }
    __syncthreads();
#pragma unroll
    for (int p = 0; p < 4; ++p) {
      int c = p * 512 + tid;
      int t = c >> 4, c16 = c & 15;
      bf16x8 v = *(const bf16x8*)(smb + t * 256 + ((c16 * 16) ^ ((t & 7) << 4)));
      *(bf16x8*)&Kb[(size_t)(m0 + t) * Hn + c16 * 8] = v;
    }
  }
  // Q (which=1), V (which=2): transposed, LDS layout [h][t]
  int bb = m0 >> 9, tt0 = m0 & (Tn - 1);
#pragma unroll
  for (int which = 1; which < 3; ++which) {
    const float* bias = (which == 1) ? bq : bv;
    u16* dst = (which == 1) ? QT : VT;
    __syncthreads();      // prev bounce's LDS reads done
#pragma unroll
    for (int n = 0; n < 2; ++n) {
      int nl = wc * 32 + n * 16 + col0;
      float bs = bias[nl];
#pragma unroll
      for (int m = 0; m < 4; ++m)
#pragma unroll
        for (int r = 0; r < 4; ++r) {
          int tl = wr * 64 + m * 16 + rg * 4 + r;
          float x = acc[which][m][n][r] + bs;
          *(u16*)(smb + nl * 256 + ((tl * 2) ^ ((nl & 7) << 4))) = f2bf(x / (1.f + __expf(-x)));
        }
    }
    __syncthreads();
#pragma unroll
    for (int p = 0; p < 4; ++p) {
      int c = p * 512 + tid;
      int h = c >> 4, c16 = c & 15;
      bf16x8 v = *(const bf16x8*)(smb + h * 256 + ((c16 * 16) ^ ((h & 7) << 4)));
      *(bf16x8*)&dst[((size_t)bb * Hn + h) * Tn + tt0 + c16 * 8] = v;
    }
  }
}

// ---------- stage 2: Q2 = (dagT @ Q)/sqrt(H) AND Vd = dagT @ V, h-split + coalesced epilogue ----------
// grid 1024 (XCD-swizzled), 256 threads (4 waves). Block: 64 q-rows x 64 h.
__global__ __launch_bounds__(256, 4) void dagqv2(
    const u16* __restrict__ dagT, const u16* __restrict__ QT,
    const u16* __restrict__ VT, u16* __restrict__ Q2, float* __restrict__ Vd) {
  __shared__ u16 sm[12288];  // 24KB: A | Q | V; reused for epilogue bounce
  int bid = blockIdx.x;
  int xcd = bid & 7, rst = bid >> 3;       // rst 0..127
  int sub = rst & 15, b = (rst >> 4) * 8 + xcd;
  int qblk = sub >> 1, hblk = sub & 1;
  int m0 = qblk * 64, h0 = hblk * 64;
  int tid = threadIdx.x, lane = tid & 63, wave = tid >> 6;
  int col0 = lane & 15, rg = lane >> 4, kcb = rg * 16;
  int swl = (col0 & 7) << 4;
  const char* Ab = (const char*)(dagT + (size_t)m0 * Tn);
  const char* Qb = (const char*)(QT + ((size_t)b * Hn + h0) * Tn);
  const char* Vb = (const char*)(VT + ((size_t)b * Hn + h0) * Tn);
  char* smb = (char*)sm;
  f32x4 accq[4] = {};
  f32x4 accv[4] = {};

  for (int kt = 0; kt < Tn; kt += 64) {
#pragma unroll
    for (int q = 0; q < 2; ++q) {
      int ch = wave * 2 + q;               // 0..7
      int flat = ch * 1024 + lane * 16;
      int row = flat >> 7, colb = flat & 127;
      int sw = (row & 7) << 4;
      gload16(Ab + (size_t)row * 1024 + kt * 2 + (colb ^ sw), smb + ch * 1024);
      gload16(Qb + (size_t)row * 1024 + kt * 2 + (colb ^ sw), smb + 8192 + ch * 1024);
      gload16(Vb + (size_t)row * 1024 + kt * 2 + (colb ^ sw), smb + 16384 + ch * 1024);
    }
    __syncthreads();
    bf16x8 af[2], fq[4][2], fv[4][2];
#pragma unroll
    for (int kk = 0; kk < 2; ++kk)
      af[kk] = *(const bf16x8*)(smb + (wave * 16 + col0) * 128 + ((kk * 64 + kcb) ^ swl));
#pragma unroll
    for (int n = 0; n < 4; ++n)
#pragma unroll
      for (int kk = 0; kk < 2; ++kk) {
        fq[n][kk] = *(const bf16x8*)(smb + 8192 + (n * 16 + col0) * 128 + ((kk * 64 + kcb) ^ swl));
        fv[n][kk] = *(const bf16x8*)(smb + 16384 + (n * 16 + col0) * 128 + ((kk * 64 + kcb) ^ swl));
      }
#pragma unroll
    for (int kk = 0; kk < 2; ++kk)
#pragma unroll
      for (int n = 0; n < 4; ++n) {
        accq[n] = __builtin_amdgcn_mfma_f32_16x16x32_bf16(af[kk], fq[n][kk], accq[n], 0, 0, 0);
        accv[n] = __builtin_amdgcn_mfma_f32_16x16x32_bf16(af[kk], fv[n][kk], accv[n], 0, 0, 0);
      }
    __syncthreads();
  }

  // ---- epilogue bounce: Vd fp32 -> [0,16K), Q2 bf16 -> [16K,24K) ----
  const float scale = 0.08838834764831845f;
#pragma unroll
  for (int n = 0; n < 4; ++n) {
    int h = n * 16 + col0;
#pragma unroll
    for (int r = 0; r < 4; ++r) {
      int q = wave * 16 + rg * 4 + r;
      int sw = (q & 7) << 4;
      *(float*)(smb + q * 256 + ((h * 4) ^ sw)) = accv[n][r];
      *(u16*)(smb + 16384 + q * 128 + ((h * 2) ^ sw)) = f2bf(accq[n][r] * scale);
    }
  }
  __syncthreads();
#pragma unroll
  for (int k = 0; k < 4; ++k) {
    int c = k * 256 + tid;
    int q = c >> 4, c16 = c & 15;
    float4 v = *(const float4*)(smb + q * 256 + ((c16 * 16) ^ ((q & 7) << 4)));
    *(float4*)&Vd[((size_t)b * Tn + m0 + q) * Hn + h0 + c16 * 4] = v;
  }
#pragma unroll
  for (int k = 0; k < 2; ++k) {
    int c = k * 256 + tid;
    int q = c >> 3, c16 = c & 7;
    bf16x8 v = *(const bf16x8*)(smb + 16384 + q * 128 + ((c16 * 16) ^ ((q & 7) << 4)));
    *(bf16x8*)&Q2[((size_t)b * Tn + m0 + q) * Hn + h0 + c16 * 8] = v;
  }
}

// ---------- stage 3+4: swapped-QK^T attention, BM=64, 2 blocks/CU ----------
// grid 512 (XCD-swizzled: 8 q-blocks of one b on one XCD), 256 threads (4 waves).
// S-phase: wave w owns queries w*16..w*16+15 (lane col0 = query). K chunks
// double-buffered via global_load_lds. PV: wave w owns h-cols w*32..w*32+31.
__global__ __launch_bounds__(256, 2) void attn_swap2(
    const u16* __restrict__ Q2, const u16* __restrict__ Kb,
    const u64* __restrict__ dbits, const u16* __restrict__ VT,
    const float* __restrict__ Vd, float* __restrict__ O) {
  __shared__ u16 smK[2][16384];    // 2 x 32KB K chunk (swizzled); smK[0] reused for P (16KB)
  __shared__ float linv[64];

  int bid = blockIdx.x;
  int xcd = bid & 7, rst = bid >> 3;       // rst 0..63
  int bx = rst & 7, b = (rst >> 3) * 8 + xcd;
  int m0 = bx * 64;
  int tid = threadIdx.x, lane = tid & 63, wave = tid >> 6;   // 4 waves
  int col0 = lane & 15, g = lane >> 4;
  int swl = (col0 & 7) << 4;

  const char* Kb0 = (const char*)(Kb + (size_t)b * Tn * Hn);

  // ---- Q fragments (this wave's 16 queries) + mask words ----
  const char* Qrow = (const char*)(Q2 + ((size_t)b * Tn + m0 + wave * 16 + col0) * Hn) + g * 16;
  bf16x8 bq[4];
#pragma unroll
  for (int kk = 0; kk < 4; ++kk) bq[kk] = *(const bf16x8*)(Qrow + kk * 64);
  const u64* dbq = dbits + (size_t)(m0 + wave * 16 + col0) * 8;
  u64 md[8];
#pragma unroll
  for (int w = 0; w < 8; ++w) md[w] = dbq[w];

#define STAGE_K(c_, buf_)                                                      \
  {                                                                            \
    _Pragma("unroll")                                                          \
    for (int q = 0; q < 8; ++q) {                                              \
      int ch = wave * 8 + q;                                                   \
      int flat = ch * 1024 + lane * 16;                                        \
      int row = flat >> 8, colb = flat & 255;                                  \
      gload16(Kb0 + (size_t)((c_) * 128 + row) * 256 + (colb ^ ((row & 7) << 4)), \
              (char*)smK[(buf_)] + ch * 1024);                                 \
    }                                                                          \
  }

  STAGE_K(0, 0);
  __syncthreads();

  // ---- S^T = K Q2^T, chunked over 4 K-tiles of 128 keys ----
  f32x4 sa[32] = {};
#pragma unroll
  for (int c = 0; c < 4; ++c) {
    if (c < 3) STAGE_K(c + 1, (c + 1) & 1);
    const char* kb = (const char*)smK[c & 1];
#pragma unroll
    for (int t = 0; t < 8; ++t)
#pragma unroll
      for (int kk = 0; kk < 4; ++kk) {
        bf16x8 ak = *(const bf16x8*)(kb + (t * 16 + col0) * 256 + ((kk * 64 + g * 16) ^ swl));
        sa[c * 8 + t] = __builtin_amdgcn_mfma_f32_16x16x32_bf16(ak, bq[kk], sa[c * 8 + t], 0, 0, 0);
      }
    if (c < 3) __syncthreads();
  }

  // ---- mask + max (lane-local + 2 shfl) ----
  float mx = -INFINITY;
#pragma unroll
  for (int t = 0; t < 32; ++t)
#pragma unroll
    for (int r = 0; r < 4; ++r) {
      int k = t * 16 + g * 4 + r;
      float v = ((md[k >> 6] >> (k & 63)) & 1) ? sa[t][r] : -INFINITY;
      sa[t][r] = v;
      mx = fmaxf(mx, v);
    }
  mx = fmaxf(mx, __shfl_xor(mx, 16, 64));
  mx = fmaxf(mx, __shfl_xor(mx, 32, 64));
  float mm = (mx == -INFINITY) ? 0.f : mx;

  // ---- exp (unnormalized), pack to bf16, row sum ----
  ushort4 pk[32];
  float s = 0.f;
#pragma unroll
  for (int t = 0; t < 32; ++t) {
    ushort4 p;
#pragma unroll
    for (int r = 0; r < 4; ++r) {
      float v = sa[t][r];
      float e = (v == -INFINITY) ? 0.f : __expf(v - mm);
      s += e;
      ((u16*)&p)[r] = f2bf(e);
    }
    pk[t] = p;
  }
  s += __shfl_xor(s, 16, 64);
  s += __shfl_xor(s, 32, 64);
  if (g == 0) linv[wave * 16 + col0] = (s > 0.f) ? (1.f / s) : 0.f;

  // ---- PV over 4 key chunks; P chunk (64x128 = 16KB) lives in smK[0] ----
  char* smP = (char*)smK[0];
  f32x4 acco[4][2] = {};
  const char* Vb = (const char*)(VT + (size_t)b * Hn * Tn);
  int qrow = wave * 16 + col0;
  int sww = (qrow & 7) << 4;

#pragma unroll
  for (int c = 0; c < 4; ++c) {
    __syncthreads();                       // prev-chunk smP reads done (c=0: S/softmax done)
#pragma unroll
    for (int tt = 0; tt < 8; ++tt)
      *(ushort4*)(smP + qrow * 256 + ((tt * 32 + g * 8) ^ sww)) = pk[c * 8 + tt];
    __syncthreads();                       // P chunk + (c=0) linv visible

#pragma unroll
    for (int kk = 0; kk < 4; ++kk) {
      bf16x8 pa[4], vb[2];
#pragma unroll
      for (int m = 0; m < 4; ++m) {
        int row = m * 16 + col0;           // 64 q-rows
        pa[m] = *(const bf16x8*)(smP + row * 256 + ((kk * 64 + g * 16) ^ ((row & 7) << 4)));
      }
#pragma unroll
      for (int n = 0; n < 2; ++n)
        vb[n] = *(const bf16x8*)(Vb + (size_t)(wave * 32 + n * 16 + col0) * 1024 + c * 256 + kk * 64 + g * 16);
#pragma unroll
      for (int m = 0; m < 4; ++m)
#pragma unroll
        for (int n = 0; n < 2; ++n)
          acco[m][n] = __builtin_amdgcn_mfma_f32_16x16x32_bf16(pa[m], vb[n], acco[m][n], 0, 0, 0);
    }
  }

  // ---- epilogue: O = acco * linv(q) + Vd ----
  const float* Vdb = Vd + ((size_t)b * Tn + m0) * Hn;
#pragma unroll
  for (int m = 0; m < 4; ++m)
#pragma unroll
    for (int r = 0; r < 4; ++r) {
      int ql = m * 16 + g * 4 + r;         // block-local q in [0,64)
      float inv = linv[ql];
      int i = m0 + ql;
#pragma unroll
      for (int n = 0; n < 2; ++n) {
        int h = wave * 32 + n * 16 + col0;
        O[((size_t)b * Tn + i) * Hn + h] = acco[m][n][r] * inv + Vdb[(size_t)ql * Hn + h];
      }
    }
}

extern "C" void kernel_launch(void* const* d_in, const int* in_sizes, int n_in,
                              void* d_out, int out_size, void* d_ws, size_t ws_size,
                              hipStream_t stream) {
  const float* X   = (const float*)d_in[0];
  const float* dag = (const float*)d_in[1];
  const float* Wk  = (const float*)d_in[2];
  const float* bk  = (const float*)d_in[3];
  const float* Wq  = (const float*)d_in[4];
  const float* bq  = (const float*)d_in[5];
  const float* Wv  = (const float*)d_in[6];
  const float* bv  = (const float*)d_in[7];
  float* O = (float*)d_out;

  char* ws = (char*)d_ws;
  u16* Wcat = (u16*)(ws);                 //    393,216
  u16* dagT = (u16*)(ws + 393216);        //    524,288
  u64* dbits= (u64*)(ws + 917504);        //     32,768
  u16* Kb   = (u16*)(ws + 950272);        //  8,388,608
  u16* QT   = (u16*)(ws + 9338880);       //  8,388,608
  u16* VT   = (u16*)(ws + 17727488);      //  8,388,608
  u16* Q2   = (u16*)(ws + 26116096);      //  8,388,608
  float* Vd = (float*)(ws + 34504704);    // 16,777,216  (end 51,281,920)

  conv_w3<<<192, 256, 0, stream>>>((const float4*)Wk, (const float4*)Wq,
                                   (const float4*)Wv, (ushort4*)Wcat);
  dag_tr<<<64, 256, 0, stream>>>(dag, dagT, dbits);

  qkv3<<<BT / 128, 512, 0, stream>>>(X, Wcat, bk, bq, bv, Kb, QT, VT);
  dagqv2<<<1024, 256, 0, stream>>>(dagT, QT, VT, Q2, Vd);
  attn_swap2<<<512, 256, 0, stream>>>(Q2, Kb, dbits, VT, Vd, O);
}

// Round 12
// 80.607 us; speedup vs baseline: 1.0316x; 1.0316x over previous
//
#include <hip/hip_runtime.h>
#include <hip/hip_bf16.h>

#define Bn 64
#define Tn 512
#define Dn 512
#define Hn 128
#define BT (Bn*Tn)

typedef unsigned short u16;
typedef unsigned long long u64;
typedef __attribute__((ext_vector_type(8))) short bf16x8;
typedef __attribute__((ext_vector_type(4))) float f32x4;

__device__ __forceinline__ u16 f2bf(float f) {
  union { float f; unsigned u; } v; v.f = f;
  unsigned r = (v.u + 0x7FFFu + ((v.u >> 16) & 1u)) >> 16;
  return (u16)r;
}

__device__ __forceinline__ bf16x8 pack8(float4 a, float4 b) {
  bf16x8 o;
  o[0] = (short)f2bf(a.x); o[1] = (short)f2bf(a.y);
  o[2] = (short)f2bf(a.z); o[3] = (short)f2bf(a.w);
  o[4] = (short)f2bf(b.x); o[5] = (short)f2bf(b.y);
  o[6] = (short)f2bf(b.z); o[7] = (short)f2bf(b.w);
  return o;
}

// async global->LDS, 16B/lane; LDS dest = wave-uniform base (+lane*16 by HW)
__device__ __forceinline__ void gload16(const void* g, void* lds) {
  __builtin_amdgcn_global_load_lds(
      (const __attribute__((address_space(1))) unsigned int*)g,
      (__attribute__((address_space(3))) unsigned int*)lds, 16, 0, 0);
}

// ---------- prep: all three W -> bf16 (one launch) ----------
__global__ __launch_bounds__(256) void conv_w3(const float4* __restrict__ Wk,
                                               const float4* __restrict__ Wq,
                                               const float4* __restrict__ Wv,
                                               ushort4* __restrict__ out) {
  int idx = blockIdx.x * 256 + threadIdx.x;        // 3 * 16384
  int which = idx >> 14, j = idx & 16383;
  const float4* src = (which == 0) ? Wk : (which == 1) ? Wq : Wv;
  float4 v = src[j];
  ushort4 o; o.x = f2bf(v.x); o.y = f2bf(v.y); o.z = f2bf(v.z); o.w = f2bf(v.w);
  out[idx] = o;
}

// ---------- prep: dag transpose + bf16 + mask bits (fused) ----------
__global__ __launch_bounds__(256) void dag_tr(const float* __restrict__ dag,
                                              u16* __restrict__ dagT,
                                              u64* __restrict__ bits) {
  __shared__ float s[64][65];
  int bx = blockIdx.x & 7, by = blockIdx.x >> 3;
  int r0 = by * 64, c0 = bx * 64;
  int t = threadIdx.x;
  int c4 = t & 15, rr = t >> 4;
#pragma unroll
  for (int q = 0; q < 4; ++q) {
    int r = rr + q * 16;
    float4 v = *(const float4*)&dag[(size_t)(r0 + r) * Tn + c0 + c4 * 4];
    s[c4 * 4 + 0][r] = v.x; s[c4 * 4 + 1][r] = v.y;
    s[c4 * 4 + 2][r] = v.z; s[c4 * 4 + 3][r] = v.w;
  }
  __syncthreads();
#pragma unroll
  for (int q = 0; q < 4; ++q) {
    int il = rr + q * 16;
    ushort4 o;
    u64 b4 = 0;
#pragma unroll
    for (int r = 0; r < 4; ++r) {
      float v = s[il][c4 * 4 + r];
      ((u16*)&o)[r] = f2bf(v);
      b4 |= (u64)(v != 0.f) << (c4 * 4 + r);
    }
    *(ushort4*)&dagT[(size_t)(c0 + il) * Tn + r0 + c4 * 4] = o;
    b4 |= __shfl_xor(b4, 1, 64);
    b4 |= __shfl_xor(b4, 2, 64);
    b4 |= __shfl_xor(b4, 4, 64);
    b4 |= __shfl_xor(b4, 8, 64);
    if (c4 == 0) bits[(size_t)(c0 + il) * 8 + (r0 >> 6)] = b4;
  }
}

// ---------- stage 1: K,Q,V = swish(X W^T + b); BM=64, 2 blocks/CU ----------
// grid BT/64 = 512, 256 threads (4 waves; wave w owns h-cols w*32..w*32+31 of all 3 outputs).
// LDS 56KB: A(8KB) | Bk | Bq | Bv (16KB each); reused for epilogue bounce.
__global__ __launch_bounds__(256, 2) void qkv3(
    const float* __restrict__ X, const u16* __restrict__ Wcat,
    const float* __restrict__ bk, const float* __restrict__ bq,
    const float* __restrict__ bv,
    u16* __restrict__ Kb, u16* __restrict__ QT, u16* __restrict__ VT) {
  __shared__ u16 sm[28672];
  int m0 = blockIdx.x * 64;
  int tid = threadIdx.x, lane = tid & 63, wave = tid >> 6;
  int col0 = lane & 15, rg = lane >> 4, kcb = rg * 16;
  int swl = (col0 & 7) << 4;
  int xrow = tid >> 2, xcq = tid & 3;      // X staging: row (0..63), 16-elem quarter
  f32x4 acc[3][4][2] = {};
  const char* Wb = (const char*)Wcat;
  char* smb = (char*)sm;

  for (int kt = 0; kt < Dn; kt += 64) {
    // A: reg-stage X fp32 -> bf16, swizzled LDS write (8KB)
    {
      const float4* src = (const float4*)(X + (size_t)(m0 + xrow) * Dn + kt + xcq * 16);
      float4 a0 = src[0], a1 = src[1], a2 = src[2], a3 = src[3];
      int sw = (xrow & 7) << 4;
      *(bf16x8*)(smb + xrow * 128 + ((xcq * 32) ^ sw)) = pack8(a0, a1);
      *(bf16x8*)(smb + xrow * 128 + ((xcq * 32 + 16) ^ sw)) = pack8(a2, a3);
    }
    // W: 48KB via gload16, pre-swizzled source (12 issues/thread)
#pragma unroll
    for (int q = 0; q < 12; ++q) {
      int c2 = wave * 12 + q;              // 0..47
      int which = c2 >> 4, idx = c2 & 15;
      int flat = idx * 1024 + lane * 16;
      int row = flat >> 7, colb = flat & 127;
      int sw = (row & 7) << 4;
      gload16(Wb + (size_t)which * 131072 + (size_t)row * 1024 + (kt << 1) + (colb ^ sw),
              smb + 8192 + which * 16384 + idx * 1024);
    }
    __syncthreads();
    bf16x8 af[4][2];
#pragma unroll
    for (int m = 0; m < 4; ++m)
#pragma unroll
      for (int kk = 0; kk < 2; ++kk)
        af[m][kk] = *(const bf16x8*)(smb + (m * 16 + col0) * 128 + ((kk * 64 + kcb) ^ swl));
#pragma unroll
    for (int which = 0; which < 3; ++which) {
      bf16x8 bfr[2][2];
#pragma unroll
      for (int n = 0; n < 2; ++n)
#pragma unroll
        for (int kk = 0; kk < 2; ++kk)
          bfr[n][kk] = *(const bf16x8*)(smb + 8192 + which * 16384 +
                                        (wave * 32 + n * 16 + col0) * 128 + ((kk * 64 + kcb) ^ swl));
#pragma unroll
      for (int kk = 0; kk < 2; ++kk)
#pragma unroll
        for (int m = 0; m < 4; ++m)
#pragma unroll
          for (int n = 0; n < 2; ++n)
            acc[which][m][n] = __builtin_amdgcn_mfma_f32_16x16x32_bf16(
                af[m][kk], bfr[n][kk], acc[which][m][n], 0, 0, 0);
    }
    __syncthreads();
  }

  // ---- epilogue: bounce each output through LDS -> full-line global stores ----
  // K (which=0): LDS layout [t][h], 16KB
  {
#pragma unroll
    for (int n = 0; n < 2; ++n) {
      int nl = wave * 32 + n * 16 + col0;
      float bs = bk[nl];
#pragma unroll
      for (int m = 0; m < 4; ++m)
#pragma unroll
        for (int r = 0; r < 4; ++r) {
          int tl = m * 16 + rg * 4 + r;    // 0..63
          float x = acc[0][m][n][r] + bs;
          *(u16*)(smb + tl * 256 + ((nl * 2) ^ ((tl & 7) << 4))) = f2bf(x / (1.f + __expf(-x)));
        }
    }
    __syncthreads();
#pragma unroll
    for (int p = 0; p < 4; ++p) {
      int c = p * 256 + tid;               // 1024 x 16B
      int t = c >> 4, c16 = c & 15;
      bf16x8 v = *(const bf16x8*)(smb + t * 256 + ((c16 * 16) ^ ((t & 7) << 4)));
      *(bf16x8*)&Kb[(size_t)(m0 + t) * Hn + c16 * 8] = v;
    }
  }
  // Q (which=1), V (which=2): transposed, LDS layout [h][t] (16KB, 128B rows)
  int bb = m0 >> 9, tt0 = m0 & (Tn - 1);
#pragma unroll
  for (int which = 1; which < 3; ++which) {
    const float* bias = (which == 1) ? bq : bv;
    u16* dst = (which == 1) ? QT : VT;
    __syncthreads();      // prev bounce's LDS reads done
#pragma unroll
    for (int n = 0; n < 2; ++n) {
      int nl = wave * 32 + n * 16 + col0;
      float bs = bias[nl];
#pragma unroll
      for (int m = 0; m < 4; ++m)
#pragma unroll
        for (int r = 0; r < 4; ++r) {
          int tl = m * 16 + rg * 4 + r;
          float x = acc[which][m][n][r] + bs;
          *(u16*)(smb + nl * 128 + ((tl * 2) ^ ((nl & 7) << 4))) = f2bf(x / (1.f + __expf(-x)));
        }
    }
    __syncthreads();
#pragma unroll
    for (int p = 0; p < 4; ++p) {
      int c = p * 256 + tid;               // 1024 x 16B
      int h = c >> 3, c8 = c & 7;
      bf16x8 v = *(const bf16x8*)(smb + h * 128 + ((c8 * 16) ^ ((h & 7) << 4)));
      *(bf16x8*)&dst[((size_t)bb * Hn + h) * Tn + tt0 + c8 * 8] = v;
    }
  }
}

// ---------- stage 2: Q2 = (dagT @ Q)/sqrt(H) AND Vd = dagT @ V, h-split + coalesced epilogue ----------
// grid 1024 (XCD-swizzled), 256 threads (4 waves). Block: 64 q-rows x 64 h.
__global__ __launch_bounds__(256, 4) void dagqv2(
    const u16* __restrict__ dagT, const u16* __restrict__ QT,
    const u16* __restrict__ VT, u16* __restrict__ Q2, float* __restrict__ Vd) {
  __shared__ u16 sm[12288];  // 24KB: A | Q | V; reused for epilogue bounce
  int bid = blockIdx.x;
  int xcd = bid & 7, rst = bid >> 3;       // rst 0..127
  int sub = rst & 15, b = (rst >> 4) * 8 + xcd;
  int qblk = sub >> 1, hblk = sub & 1;
  int m0 = qblk * 64, h0 = hblk * 64;
  int tid = threadIdx.x, lane = tid & 63, wave = tid >> 6;
  int col0 = lane & 15, rg = lane >> 4, kcb = rg * 16;
  int swl = (col0 & 7) << 4;
  const char* Ab = (const char*)(dagT + (size_t)m0 * Tn);
  const char* Qb = (const char*)(QT + ((size_t)b * Hn + h0) * Tn);
  const char* Vb = (const char*)(VT + ((size_t)b * Hn + h0) * Tn);
  char* smb = (char*)sm;
  f32x4 accq[4] = {};
  f32x4 accv[4] = {};

  for (int kt = 0; kt < Tn; kt += 64) {
#pragma unroll
    for (int q = 0; q < 2; ++q) {
      int ch = wave * 2 + q;               // 0..7
      int flat = ch * 1024 + lane * 16;
      int row = flat >> 7, colb = flat & 127;
      int sw = (row & 7) << 4;
      gload16(Ab + (size_t)row * 1024 + kt * 2 + (colb ^ sw), smb + ch * 1024);
      gload16(Qb + (size_t)row * 1024 + kt * 2 + (colb ^ sw), smb + 8192 + ch * 1024);
      gload16(Vb + (size_t)row * 1024 + kt * 2 + (colb ^ sw), smb + 16384 + ch * 1024);
    }
    __syncthreads();
    bf16x8 af[2], fq[4][2], fv[4][2];
#pragma unroll
    for (int kk = 0; kk < 2; ++kk)
      af[kk] = *(const bf16x8*)(smb + (wave * 16 + col0) * 128 + ((kk * 64 + kcb) ^ swl));
#pragma unroll
    for (int n = 0; n < 4; ++n)
#pragma unroll
      for (int kk = 0; kk < 2; ++kk) {
        fq[n][kk] = *(const bf16x8*)(smb + 8192 + (n * 16 + col0) * 128 + ((kk * 64 + kcb) ^ swl));
        fv[n][kk] = *(const bf16x8*)(smb + 16384 + (n * 16 + col0) * 128 + ((kk * 64 + kcb) ^ swl));
      }
#pragma unroll
    for (int kk = 0; kk < 2; ++kk)
#pragma unroll
      for (int n = 0; n < 4; ++n) {
        accq[n] = __builtin_amdgcn_mfma_f32_16x16x32_bf16(af[kk], fq[n][kk], accq[n], 0, 0, 0);
        accv[n] = __builtin_amdgcn_mfma_f32_16x16x32_bf16(af[kk], fv[n][kk], accv[n], 0, 0, 0);
      }
    __syncthreads();
  }

  // ---- epilogue bounce: Vd fp32 -> [0,16K), Q2 bf16 -> [16K,24K) ----
  const float scale = 0.08838834764831845f;
#pragma unroll
  for (int n = 0; n < 4; ++n) {
    int h = n * 16 + col0;
#pragma unroll
    for (int r = 0; r < 4; ++r) {
      int q = wave * 16 + rg * 4 + r;
      int sw = (q & 7) << 4;
      *(float*)(smb + q * 256 + ((h * 4) ^ sw)) = accv[n][r];
      *(u16*)(smb + 16384 + q * 128 + ((h * 2) ^ sw)) = f2bf(accq[n][r] * scale);
    }
  }
  __syncthreads();
#pragma unroll
  for (int k = 0; k < 4; ++k) {
    int c = k * 256 + tid;
    int q = c >> 4, c16 = c & 15;
    float4 v = *(const float4*)(smb + q * 256 + ((c16 * 16) ^ ((q & 7) << 4)));
    *(float4*)&Vd[((size_t)b * Tn + m0 + q) * Hn + h0 + c16 * 4] = v;
  }
#pragma unroll
  for (int k = 0; k < 2; ++k) {
    int c = k * 256 + tid;
    int q = c >> 3, c16 = c & 7;
    bf16x8 v = *(const bf16x8*)(smb + 16384 + q * 128 + ((c16 * 16) ^ ((q & 7) << 4)));
    *(bf16x8*)&Q2[((size_t)b * Tn + m0 + q) * Hn + h0 + c16 * 8] = v;
  }
}

// ---------- stage 3+4: swapped-QK^T attention, BM=64, 2 blocks/CU ----------
// grid 512 (XCD-swizzled), 256 threads (4 waves).
__global__ __launch_bounds__(256, 2) void attn_swap2(
    const u16* __restrict__ Q2, const u16* __restrict__ Kb,
    const u64* __restrict__ dbits, const u16* __restrict__ VT,
    const float* __restrict__ Vd, float* __restrict__ O) {
  __shared__ u16 smK[2][16384];    // 2 x 32KB K chunk (swizzled); smK[0] reused for P (16KB)
  __shared__ float linv[64];

  int bid = blockIdx.x;
  int xcd = bid & 7, rst = bid >> 3;       // rst 0..63
  int bx = rst & 7, b = (rst >> 3) * 8 + xcd;
  int m0 = bx * 64;
  int tid = threadIdx.x, lane = tid & 63, wave = tid >> 6;   // 4 waves
  int col0 = lane & 15, g = lane >> 4;
  int swl = (col0 & 7) << 4;

  const char* Kb0 = (const char*)(Kb + (size_t)b * Tn * Hn);

  // ---- Q fragments (this wave's 16 queries) + mask words ----
  const char* Qrow = (const char*)(Q2 + ((size_t)b * Tn + m0 + wave * 16 + col0) * Hn) + g * 16;
  bf16x8 bq[4];
#pragma unroll
  for (int kk = 0; kk < 4; ++kk) bq[kk] = *(const bf16x8*)(Qrow + kk * 64);
  const u64* dbq = dbits + (size_t)(m0 + wave * 16 + col0) * 8;
  u64 md[8];
#pragma unroll
  for (int w = 0; w < 8; ++w) md[w] = dbq[w];

#define STAGE_K(c_, buf_)                                                      \
  {                                                                            \
    _Pragma("unroll")                                                          \
    for (int q = 0; q < 8; ++q) {                                              \
      int ch = wave * 8 + q;                                                   \
      int flat = ch * 1024 + lane * 16;                                        \
      int row = flat >> 8, colb = flat & 255;                                  \
      gload16(Kb0 + (size_t)((c_) * 128 + row) * 256 + (colb ^ ((row & 7) << 4)), \
              (char*)smK[(buf_)] + ch * 1024);                                 \
    }                                                                          \
  }

  STAGE_K(0, 0);
  __syncthreads();

  // ---- S^T = K Q2^T, chunked over 4 K-tiles of 128 keys ----
  f32x4 sa[32] = {};
#pragma unroll
  for (int c = 0; c < 4; ++c) {
    if (c < 3) STAGE_K(c + 1, (c + 1) & 1);
    const char* kb = (const char*)smK[c & 1];
#pragma unroll
    for (int t = 0; t < 8; ++t)
#pragma unroll
      for (int kk = 0; kk < 4; ++kk) {
        bf16x8 ak = *(const bf16x8*)(kb + (t * 16 + col0) * 256 + ((kk * 64 + g * 16) ^ swl));
        sa[c * 8 + t] = __builtin_amdgcn_mfma_f32_16x16x32_bf16(ak, bq[kk], sa[c * 8 + t], 0, 0, 0);
      }
    if (c < 3) __syncthreads();
  }

  // ---- mask + max (lane-local + 2 shfl) ----
  float mx = -INFINITY;
#pragma unroll
  for (int t = 0; t < 32; ++t)
#pragma unroll
    for (int r = 0; r < 4; ++r) {
      int k = t * 16 + g * 4 + r;
      float v = ((md[k >> 6] >> (k & 63)) & 1) ? sa[t][r] : -INFINITY;
      sa[t][r] = v;
      mx = fmaxf(mx, v);
    }
  mx = fmaxf(mx, __shfl_xor(mx, 16, 64));
  mx = fmaxf(mx, __shfl_xor(mx, 32, 64));
  float mm = (mx == -INFINITY) ? 0.f : mx;

  // ---- exp (unnormalized), pack to bf16, row sum ----
  ushort4 pk[32];
  float s = 0.f;
#pragma unroll
  for (int t = 0; t < 32; ++t) {
    ushort4 p;
#pragma unroll
    for (int r = 0; r < 4; ++r) {
      float v = sa[t][r];
      float e = (v == -INFINITY) ? 0.f : __expf(v - mm);
      s += e;
      ((u16*)&p)[r] = f2bf(e);
    }
    pk[t] = p;
  }
  s += __shfl_xor(s, 16, 64);
  s += __shfl_xor(s, 32, 64);
  if (g == 0) linv[wave * 16 + col0] = (s > 0.f) ? (1.f / s) : 0.f;

  // ---- PV over 4 key chunks; P chunk (64x128 = 16KB) lives in smK[0] ----
  char* smP = (char*)smK[0];
  f32x4 acco[4][2] = {};
  const char* Vb = (const char*)(VT + (size_t)b * Hn * Tn);
  int qrow = wave * 16 + col0;
  int sww = (qrow & 7) << 4;

#pragma unroll
  for (int c = 0; c < 4; ++c) {
    __syncthreads();                       // prev-chunk smP reads done (c=0: S/softmax done)
#pragma unroll
    for (int tt = 0; tt < 8; ++tt)
      *(ushort4*)(smP + qrow * 256 + ((tt * 32 + g * 8) ^ sww)) = pk[c * 8 + tt];
    __syncthreads();                       // P chunk + (c=0) linv visible

#pragma unroll
    for (int kk = 0; kk < 4; ++kk) {
      bf16x8 pa[4], vb[2];
#pragma unroll
      for (int m = 0; m < 4; ++m) {
        int row = m * 16 + col0;           // 64 q-rows
        pa[m] = *(const bf16x8*)(smP + row * 256 + ((kk * 64 + g * 16) ^ ((row & 7) << 4)));
      }
#pragma unroll
      for (int n = 0; n < 2; ++n)
        vb[n] = *(const bf16x8*)(Vb + (size_t)(wave * 32 + n * 16 + col0) * 1024 + c * 256 + kk * 64 + g * 16);
#pragma unroll
      for (int m = 0; m < 4; ++m)
#pragma unroll
        for (int n = 0; n < 2; ++n)
          acco[m][n] = __builtin_amdgcn_mfma_f32_16x16x32_bf16(pa[m], vb[n], acco[m][n], 0, 0, 0);
    }
  }

  // ---- epilogue: O = acco * linv(q) + Vd ----
  const float* Vdb = Vd + ((size_t)b * Tn + m0) * Hn;
#pragma unroll
  for (int m = 0; m < 4; ++m)
#pragma unroll
    for (int r = 0; r < 4; ++r) {
      int ql = m * 16 + g * 4 + r;         // block-local q in [0,64)
      float inv = linv[ql];
      int i = m0 + ql;
#pragma unroll
      for (int n = 0; n < 2; ++n) {
        int h = wave * 32 + n * 16 + col0;
        O[((size_t)b * Tn + i) * Hn + h] = acco[m][n][r] * inv + Vdb[(size_t)ql * Hn + h];
      }
    }
}

extern "C" void kernel_launch(void* const* d_in, const int* in_sizes, int n_in,
                              void* d_out, int out_size, void* d_ws, size_t ws_size,
                              hipStream_t stream) {
  const float* X   = (const float*)d_in[0];
  const float* dag = (const float*)d_in[1];
  const float* Wk  = (const float*)d_in[2];
  const float* bk  = (const float*)d_in[3];
  const float* Wq  = (const float*)d_in[4];
  const float* bq  = (const float*)d_in[5];
  const float* Wv  = (const float*)d_in[6];
  const float* bv  = (const float*)d_in[7];
  float* O = (float*)d_out;

  char* ws = (char*)d_ws;
  u16* Wcat = (u16*)(ws);                 //    393,216
  u16* dagT = (u16*)(ws + 393216);        //    524,288
  u64* dbits= (u64*)(ws + 917504);        //     32,768
  u16* Kb   = (u16*)(ws + 950272);        //  8,388,608
  u16* QT   = (u16*)(ws + 9338880);       //  8,388,608
  u16* VT   = (u16*)(ws + 17727488);      //  8,388,608
  u16* Q2   = (u16*)(ws + 26116096);      //  8,388,608
  float* Vd = (float*)(ws + 34504704);    // 16,777,216  (end 51,281,920)

  conv_w3<<<192, 256, 0, stream>>>((const float4*)Wk, (const float4*)Wq,
                                   (const float4*)Wv, (ushort4*)Wcat);
  dag_tr<<<64, 256, 0, stream>>>(dag, dagT, dbits);

  qkv3<<<BT / 64, 256, 0, stream>>>(X, Wcat, bk, bq, bv, Kb, QT, VT);
  dagqv2<<<1024, 256, 0, stream>>>(dagT, QT, VT, Q2, Vd);
  attn_swap2<<<512, 256, 0, stream>>>(Q2, Kb, dbits, VT, Vd, O);
}

// Round 13
// 79.491 us; speedup vs baseline: 1.0460x; 1.0140x over previous
//
#include <hip/hip_runtime.h>
#include <hip/hip_bf16.h>

#define Bn 64
#define Tn 512
#define Dn 512
#define Hn 128
#define BT (Bn*Tn)

typedef unsigned short u16;
typedef unsigned long long u64;
typedef __attribute__((ext_vector_type(8))) short bf16x8;
typedef __attribute__((ext_vector_type(4))) float f32x4;

__device__ __forceinline__ u16 f2bf(float f) {
  union { float f; unsigned u; } v; v.f = f;
  unsigned r = (v.u + 0x7FFFu + ((v.u >> 16) & 1u)) >> 16;
  return (u16)r;
}

__device__ __forceinline__ bf16x8 pack8(float4 a, float4 b) {
  bf16x8 o;
  o[0] = (short)f2bf(a.x); o[1] = (short)f2bf(a.y);
  o[2] = (short)f2bf(a.z); o[3] = (short)f2bf(a.w);
  o[4] = (short)f2bf(b.x); o[5] = (short)f2bf(b.y);
  o[6] = (short)f2bf(b.z); o[7] = (short)f2bf(b.w);
  return o;
}

// async global->LDS, 16B/lane; LDS dest = wave-uniform base (+lane*16 by HW)
__device__ __forceinline__ void gload16(const void* g, void* lds) {
  __builtin_amdgcn_global_load_lds(
      (const __attribute__((address_space(1))) unsigned int*)g,
      (__attribute__((address_space(3))) unsigned int*)lds, 16, 0, 0);
}

// ---------- prep: all three W -> bf16 (one launch) ----------
__global__ __launch_bounds__(256) void conv_w3(const float4* __restrict__ Wk,
                                               const float4* __restrict__ Wq,
                                               const float4* __restrict__ Wv,
                                               ushort4* __restrict__ out) {
  int idx = blockIdx.x * 256 + threadIdx.x;        // 3 * 16384
  int which = idx >> 14, j = idx & 16383;
  const float4* src = (which == 0) ? Wk : (which == 1) ? Wq : Wv;
  float4 v = src[j];
  ushort4 o; o.x = f2bf(v.x); o.y = f2bf(v.y); o.z = f2bf(v.z); o.w = f2bf(v.w);
  out[idx] = o;
}

// ---------- prep: dag transpose + bf16 + mask bits (fused) ----------
__global__ __launch_bounds__(256) void dag_tr(const float* __restrict__ dag,
                                              u16* __restrict__ dagT,
                                              u64* __restrict__ bits) {
  __shared__ float s[64][65];
  int bx = blockIdx.x & 7, by = blockIdx.x >> 3;
  int r0 = by * 64, c0 = bx * 64;
  int t = threadIdx.x;
  int c4 = t & 15, rr = t >> 4;
#pragma unroll
  for (int q = 0; q < 4; ++q) {
    int r = rr + q * 16;
    float4 v = *(const float4*)&dag[(size_t)(r0 + r) * Tn + c0 + c4 * 4];
    s[c4 * 4 + 0][r] = v.x; s[c4 * 4 + 1][r] = v.y;
    s[c4 * 4 + 2][r] = v.z; s[c4 * 4 + 3][r] = v.w;
  }
  __syncthreads();
#pragma unroll
  for (int q = 0; q < 4; ++q) {
    int il = rr + q * 16;
    ushort4 o;
    u64 b4 = 0;
#pragma unroll
    for (int r = 0; r < 4; ++r) {
      float v = s[il][c4 * 4 + r];
      ((u16*)&o)[r] = f2bf(v);
      b4 |= (u64)(v != 0.f) << (c4 * 4 + r);
    }
    *(ushort4*)&dagT[(size_t)(c0 + il) * Tn + r0 + c4 * 4] = o;
    b4 |= __shfl_xor(b4, 1, 64);
    b4 |= __shfl_xor(b4, 2, 64);
    b4 |= __shfl_xor(b4, 4, 64);
    b4 |= __shfl_xor(b4, 8, 64);
    if (c4 == 0) bits[(size_t)(c0 + il) * 8 + (r0 >> 6)] = b4;
  }
}

// ---------- stage 1: K,Q,V = swish(X W^T + b); BM=64, 2 blocks/CU ----------
// grid BT/64 = 512, 256 threads (4 waves; wave w owns h-cols w*32..w*32+31).
__global__ __launch_bounds__(256, 2) void qkv3(
    const float* __restrict__ X, const u16* __restrict__ Wcat,
    const float* __restrict__ bk, const float* __restrict__ bq,
    const float* __restrict__ bv,
    u16* __restrict__ Kb, u16* __restrict__ QT, u16* __restrict__ VT) {
  __shared__ u16 sm[28672];
  int m0 = blockIdx.x * 64;
  int tid = threadIdx.x, lane = tid & 63, wave = tid >> 6;
  int col0 = lane & 15, rg = lane >> 4, kcb = rg * 16;
  int swl = (col0 & 7) << 4;
  int xrow = tid >> 2, xcq = tid & 3;      // X staging: row (0..63), 16-elem quarter
  f32x4 acc[3][4][2] = {};
  const char* Wb = (const char*)Wcat;
  char* smb = (char*)sm;

  for (int kt = 0; kt < Dn; kt += 64) {
    // A: reg-stage X fp32 -> bf16, swizzled LDS write (8KB)
    {
      const float4* src = (const float4*)(X + (size_t)(m0 + xrow) * Dn + kt + xcq * 16);
      float4 a0 = src[0], a1 = src[1], a2 = src[2], a3 = src[3];
      int sw = (xrow & 7) << 4;
      *(bf16x8*)(smb + xrow * 128 + ((xcq * 32) ^ sw)) = pack8(a0, a1);
      *(bf16x8*)(smb + xrow * 128 + ((xcq * 32 + 16) ^ sw)) = pack8(a2, a3);
    }
    // W: 48KB via gload16, pre-swizzled source (12 issues/thread)
#pragma unroll
    for (int q = 0; q < 12; ++q) {
      int c2 = wave * 12 + q;              // 0..47
      int which = c2 >> 4, idx = c2 & 15;
      int flat = idx * 1024 + lane * 16;
      int row = flat >> 7, colb = flat & 127;
      int sw = (row & 7) << 4;
      gload16(Wb + (size_t)which * 131072 + (size_t)row * 1024 + (kt << 1) + (colb ^ sw),
              smb + 8192 + which * 16384 + idx * 1024);
    }
    __syncthreads();
    bf16x8 af[4][2];
#pragma unroll
    for (int m = 0; m < 4; ++m)
#pragma unroll
      for (int kk = 0; kk < 2; ++kk)
        af[m][kk] = *(const bf16x8*)(smb + (m * 16 + col0) * 128 + ((kk * 64 + kcb) ^ swl));
#pragma unroll
    for (int which = 0; which < 3; ++which) {
      bf16x8 bfr[2][2];
#pragma unroll
      for (int n = 0; n < 2; ++n)
#pragma unroll
        for (int kk = 0; kk < 2; ++kk)
          bfr[n][kk] = *(const bf16x8*)(smb + 8192 + which * 16384 +
                                        (wave * 32 + n * 16 + col0) * 128 + ((kk * 64 + kcb) ^ swl));
#pragma unroll
      for (int kk = 0; kk < 2; ++kk)
#pragma unroll
        for (int m = 0; m < 4; ++m)
#pragma unroll
          for (int n = 0; n < 2; ++n)
            acc[which][m][n] = __builtin_amdgcn_mfma_f32_16x16x32_bf16(
                af[m][kk], bfr[n][kk], acc[which][m][n], 0, 0, 0);
    }
    __syncthreads();
  }

  // ---- epilogue: bounce through LDS -> full-line global stores ----
  {
#pragma unroll
    for (int n = 0; n < 2; ++n) {
      int nl = wave * 32 + n * 16 + col0;
      float bs = bk[nl];
#pragma unroll
      for (int m = 0; m < 4; ++m)
#pragma unroll
        for (int r = 0; r < 4; ++r) {
          int tl = m * 16 + rg * 4 + r;    // 0..63
          float x = acc[0][m][n][r] + bs;
          *(u16*)(smb + tl * 256 + ((nl * 2) ^ ((tl & 7) << 4))) = f2bf(x / (1.f + __expf(-x)));
        }
    }
    __syncthreads();
#pragma unroll
    for (int p = 0; p < 4; ++p) {
      int c = p * 256 + tid;               // 1024 x 16B
      int t = c >> 4, c16 = c & 15;
      bf16x8 v = *(const bf16x8*)(smb + t * 256 + ((c16 * 16) ^ ((t & 7) << 4)));
      *(bf16x8*)&Kb[(size_t)(m0 + t) * Hn + c16 * 8] = v;
    }
  }
  int bb = m0 >> 9, tt0 = m0 & (Tn - 1);
#pragma unroll
  for (int which = 1; which < 3; ++which) {
    const float* bias = (which == 1) ? bq : bv;
    u16* dst = (which == 1) ? QT : VT;
    __syncthreads();      // prev bounce's LDS reads done
#pragma unroll
    for (int n = 0; n < 2; ++n) {
      int nl = wave * 32 + n * 16 + col0;
      float bs = bias[nl];
#pragma unroll
      for (int m = 0; m < 4; ++m)
#pragma unroll
        for (int r = 0; r < 4; ++r) {
          int tl = m * 16 + rg * 4 + r;
          float x = acc[which][m][n][r] + bs;
          *(u16*)(smb + nl * 128 + ((tl * 2) ^ ((nl & 7) << 4))) = f2bf(x / (1.f + __expf(-x)));
        }
    }
    __syncthreads();
#pragma unroll
    for (int p = 0; p < 4; ++p) {
      int c = p * 256 + tid;               // 1024 x 16B
      int h = c >> 3, c8 = c & 7;
      bf16x8 v = *(const bf16x8*)(smb + h * 128 + ((c8 * 16) ^ ((h & 7) << 4)));
      *(bf16x8*)&dst[((size_t)bb * Hn + h) * Tn + tt0 + c8 * 8] = v;
    }
  }
}

// ---------- stage 2+3+4 fused: Q2/Vd (dagq) + swapped-QK^T attention ----------
// grid 512 (XCD-swizzled: 8 q-blocks of one b on one XCD), 256 threads (4 waves).
// Phase 1 (dagq): block computes Q2 = (dagT@Q)/sqrt(H) -> LDS, Vd = dagT@V -> REGISTERS
//   (wave w owns h-cols w*32..w*32+31 == its PV columns, so accv maps 1:1 onto acco).
// Phase 2 (S): S^T = K Q2^T; wave w owns queries w*16..w*16+15; lane-local softmax.
// Phase 3 (PV): O = (P@V)*linv + accv.
__global__ __launch_bounds__(256, 2) void dattn(
    const u16* __restrict__ dagT, const u16* __restrict__ QT,
    const u16* __restrict__ VT, const u16* __restrict__ Kb,
    const u64* __restrict__ dbits, float* __restrict__ O) {
  __shared__ char smA[65536];   // ph1: dag[0,8K)|Q[8K,24K)|V[24K,40K); ph2: K dbuf 2x32K; ph3: P[0,16K)
  __shared__ u16 smQ2[8192];    // 16KB Q2 [q][h] 64x256B swizzled; linv overlays offset 0 in PV phase

  int bid = blockIdx.x;
  int xcd = bid & 7, rst = bid >> 3;       // rst 0..63
  int bx = rst & 7, b = (rst >> 3) * 8 + xcd;
  int m0 = bx * 64;
  int tid = threadIdx.x, lane = tid & 63, wave = tid >> 6;   // 4 waves
  int col0 = lane & 15, g = lane >> 4;
  int swl = (col0 & 7) << 4;

  const char* Ab = (const char*)(dagT + (size_t)m0 * Tn);
  const char* Qb = (const char*)(QT + (size_t)b * Hn * Tn);
  const char* Vb = (const char*)(VT + (size_t)b * Hn * Tn);
  const char* Kb0 = (const char*)(Kb + (size_t)b * Tn * Hn);

  // ================= phase 1: dagq (Q2 -> LDS, Vd -> regs) =================
  f32x4 accq[4][2] = {};
  f32x4 accv[4][2] = {};
  for (int kt = 0; kt < Tn; kt += 64) {
#pragma unroll
    for (int q = 0; q < 2; ++q) {          // dag tile 8KB
      int ch = wave * 2 + q;
      int flat = ch * 1024 + lane * 16;
      int row = flat >> 7, colb = flat & 127;
      int sw = (row & 7) << 4;
      gload16(Ab + (size_t)row * 1024 + kt * 2 + (colb ^ sw), smA + ch * 1024);
    }
#pragma unroll
    for (int q = 0; q < 4; ++q) {          // Q,V tiles 16KB each
      int ch = wave * 4 + q;
      int flat = ch * 1024 + lane * 16;
      int row = flat >> 7, colb = flat & 127;
      int sw = (row & 7) << 4;
      gload16(Qb + (size_t)row * 1024 + kt * 2 + (colb ^ sw), smA + 8192 + ch * 1024);
      gload16(Vb + (size_t)row * 1024 + kt * 2 + (colb ^ sw), smA + 24576 + ch * 1024);
    }
    __syncthreads();
    bf16x8 af[4][2], fq[2][2], fv[2][2];
#pragma unroll
    for (int m = 0; m < 4; ++m)
#pragma unroll
      for (int kk = 0; kk < 2; ++kk)
        af[m][kk] = *(const bf16x8*)(smA + (m * 16 + col0) * 128 + ((kk * 64 + g * 16) ^ swl));
#pragma unroll
    for (int n = 0; n < 2; ++n)
#pragma unroll
      for (int kk = 0; kk < 2; ++kk) {
        fq[n][kk] = *(const bf16x8*)(smA + 8192 + (wave * 32 + n * 16 + col0) * 128 + ((kk * 64 + g * 16) ^ swl));
        fv[n][kk] = *(const bf16x8*)(smA + 24576 + (wave * 32 + n * 16 + col0) * 128 + ((kk * 64 + g * 16) ^ swl));
      }
#pragma unroll
    for (int kk = 0; kk < 2; ++kk)
#pragma unroll
      for (int m = 0; m < 4; ++m)
#pragma unroll
        for (int n = 0; n < 2; ++n) {
          accq[m][n] = __builtin_amdgcn_mfma_f32_16x16x32_bf16(af[m][kk], fq[n][kk], accq[m][n], 0, 0, 0);
          accv[m][n] = __builtin_amdgcn_mfma_f32_16x16x32_bf16(af[m][kk], fv[n][kk], accv[m][n], 0, 0, 0);
        }
    __syncthreads();
  }

  // Q2 -> LDS [q][h] (scaled); accq dies here
  const float scale = 0.08838834764831845f;
#pragma unroll
  for (int m = 0; m < 4; ++m)
#pragma unroll
    for (int n = 0; n < 2; ++n)
#pragma unroll
      for (int r = 0; r < 4; ++r) {
        int q = m * 16 + g * 4 + r;
        int h = wave * 32 + n * 16 + col0;
        *(u16*)((char*)smQ2 + q * 256 + ((h * 2) ^ ((q & 7) << 4))) = f2bf(accq[m][n][r] * scale);
      }

  // ================= phase 2: S^T = K Q2^T =================
#define STAGE_K(c_, buf_)                                                      \
  {                                                                            \
    _Pragma("unroll")                                                          \
    for (int q = 0; q < 8; ++q) {                                              \
      int ch = wave * 8 + q;                                                   \
      int flat = ch * 1024 + lane * 16;                                        \
      int row = flat >> 8, colb = flat & 255;                                  \
      gload16(Kb0 + (size_t)((c_) * 128 + row) * 256 + (colb ^ ((row & 7) << 4)), \
              smA + (buf_) * 32768 + ch * 1024);                               \
    }                                                                          \
  }

  STAGE_K(0, 0);
  __syncthreads();   // Q2 visible + K chunk 0 staged

  // Q fragments from LDS (this wave's 16 queries) + mask words from global
  int qrow = wave * 16 + col0;
  bf16x8 bq[4];
#pragma unroll
  for (int kk = 0; kk < 4; ++kk)
    bq[kk] = *(const bf16x8*)((char*)smQ2 + qrow * 256 + ((kk * 64 + g * 16) ^ ((qrow & 7) << 4)));
  const u64* dbq = dbits + (size_t)(m0 + qrow) * 8;
  u64 md[8];
#pragma unroll
  for (int w = 0; w < 8; ++w) md[w] = dbq[w];

  f32x4 sa[32] = {};
#pragma unroll
  for (int c = 0; c < 4; ++c) {
    if (c < 3) STAGE_K(c + 1, (c + 1) & 1);
    const char* kb = smA + (c & 1) * 32768;
#pragma unroll
    for (int t = 0; t < 8; ++t)
#pragma unroll
      for (int kk = 0; kk < 4; ++kk) {
        bf16x8 ak = *(const bf16x8*)(kb + (t * 16 + col0) * 256 + ((kk * 64 + g * 16) ^ swl));
        sa[c * 8 + t] = __builtin_amdgcn_mfma_f32_16x16x32_bf16(ak, bq[kk], sa[c * 8 + t], 0, 0, 0);
      }
    if (c < 3) __syncthreads();
  }

  // ---- mask + max (lane-local + 2 shfl) ----
  float mx = -INFINITY;
#pragma unroll
  for (int t = 0; t < 32; ++t)
#pragma unroll
    for (int r = 0; r < 4; ++r) {
      int k = t * 16 + g * 4 + r;
      float v = ((md[k >> 6] >> (k & 63)) & 1) ? sa[t][r] : -INFINITY;
      sa[t][r] = v;
      mx = fmaxf(mx, v);
    }
  mx = fmaxf(mx, __shfl_xor(mx, 16, 64));
  mx = fmaxf(mx, __shfl_xor(mx, 32, 64));
  float mm = (mx == -INFINITY) ? 0.f : mx;

  // ---- exp (unnormalized), pack to bf16, row sum ----
  ushort4 pk[32];
  float s = 0.f;
#pragma unroll
  for (int t = 0; t < 32; ++t) {
    ushort4 p;
#pragma unroll
    for (int r = 0; r < 4; ++r) {
      float v = sa[t][r];
      float e = (v == -INFINITY) ? 0.f : __expf(v - mm);
      s += e;
      ((u16*)&p)[r] = f2bf(e);
    }
    pk[t] = p;
  }
  s += __shfl_xor(s, 16, 64);
  s += __shfl_xor(s, 32, 64);
  float* linv = (float*)smQ2;   // smQ2 dead (all waves consumed bq before in-loop barriers)
  if (g == 0) linv[qrow] = (s > 0.f) ? (1.f / s) : 0.f;

  // ================= phase 3: PV; P chunk (64x128 = 16KB) in smA[0,16K) =================
  char* smP = smA;
  f32x4 acco[4][2] = {};
  int sww = (qrow & 7) << 4;

#pragma unroll
  for (int c = 0; c < 4; ++c) {
    __syncthreads();                       // all S reads of smA done / prev-chunk P reads done
#pragma unroll
    for (int tt = 0; tt < 8; ++tt)
      *(ushort4*)(smP + qrow * 256 + ((tt * 32 + g * 8) ^ sww)) = pk[c * 8 + tt];
    __syncthreads();                       // P chunk (+ c=0: linv) visible

#pragma unroll
    for (int kk = 0; kk < 4; ++kk) {
      bf16x8 pa[4], vb[2];
#pragma unroll
      for (int m = 0; m < 4; ++m) {
        int row = m * 16 + col0;           // 64 q-rows
        pa[m] = *(const bf16x8*)(smP + row * 256 + ((kk * 64 + g * 16) ^ ((row & 7) << 4)));
      }
#pragma unroll
      for (int n = 0; n < 2; ++n)
        vb[n] = *(const bf16x8*)(Vb + (size_t)(wave * 32 + n * 16 + col0) * 1024 + c * 256 + kk * 64 + g * 16);
#pragma unroll
      for (int m = 0; m < 4; ++m)
#pragma unroll
        for (int n = 0; n < 2; ++n)
          acco[m][n] = __builtin_amdgcn_mfma_f32_16x16x32_bf16(pa[m], vb[n], acco[m][n], 0, 0, 0);
    }
  }

  // ---- epilogue: O = acco * linv(q) + accv (same lane mapping!) ----
#pragma unroll
  for (int m = 0; m < 4; ++m)
#pragma unroll
    for (int r = 0; r < 4; ++r) {
      int ql = m * 16 + g * 4 + r;         // block-local q in [0,64)
      float inv = linv[ql];
      int i = m0 + ql;
#pragma unroll
      for (int n = 0; n < 2; ++n) {
        int h = wave * 32 + n * 16 + col0;
        O[((size_t)b * Tn + i) * Hn + h] = acco[m][n][r] * inv + accv[m][n][r];
      }
    }
#undef STAGE_K
}

extern "C" void kernel_launch(void* const* d_in, const int* in_sizes, int n_in,
                              void* d_out, int out_size, void* d_ws, size_t ws_size,
                              hipStream_t stream) {
  const float* X   = (const float*)d_in[0];
  const float* dag = (const float*)d_in[1];
  const float* Wk  = (const float*)d_in[2];
  const float* bk  = (const float*)d_in[3];
  const float* Wq  = (const float*)d_in[4];
  const float* bq  = (const float*)d_in[5];
  const float* Wv  = (const float*)d_in[6];
  const float* bv  = (const float*)d_in[7];
  float* O = (float*)d_out;

  char* ws = (char*)d_ws;
  u16* Wcat = (u16*)(ws);                 //    393,216
  u16* dagT = (u16*)(ws + 393216);        //    524,288
  u64* dbits= (u64*)(ws + 917504);        //     32,768
  u16* Kb   = (u16*)(ws + 950272);        //  8,388,608
  u16* QT   = (u16*)(ws + 9338880);       //  8,388,608
  u16* VT   = (u16*)(ws + 17727488);      //  8,388,608  (end 26,116,096)

  conv_w3<<<192, 256, 0, stream>>>((const float4*)Wk, (const float4*)Wq,
                                   (const float4*)Wv, (ushort4*)Wcat);
  dag_tr<<<64, 256, 0, stream>>>(dag, dagT, dbits);

  qkv3<<<BT / 64, 256, 0, stream>>>(X, Wcat, bk, bq, bv, Kb, QT, VT);
  dattn<<<512, 256, 0, stream>>>(dagT, QT, VT, Kb, dbits, O);
}